// Round 6
// baseline (1333.717 us; speedup 1.0000x reference)
//
#include <hip/hip_runtime.h>
#include <math.h>

#define NNODES 100000
#define NEDGES 3200000
#define NFEAT  500
#define HID    64
#define NCLS   40
#define NLAYERS 8
#define NPB    16      // spmm nodes per block (quarter-wave gather: 4 nodes/wave)
#define NBUCK  16      // src-range buckets per node list (6250 nodes = 0.8MB bf16 rows)
#define NODES_PER_BUCK 6250
#define NBIN   64      // dst-range bins for two-level build
#define NODES_PER_BIN 1563   // ceil(NNODES/NBIN)

typedef __attribute__((ext_vector_type(8))) short short8;   // 8 bf16 (4 VGPRs)
typedef __attribute__((ext_vector_type(4))) float floatx4;  // MFMA acc

static __device__ __forceinline__ float b2f(unsigned short u) {
    return __uint_as_float(((unsigned)u) << 16);
}
static __device__ __forceinline__ unsigned short f2b(float f) {
    unsigned u = __float_as_uint(f);
    return (unsigned short)((u + 0x7FFFu + ((u >> 16) & 1u)) >> 16);  // RNE
}
static __device__ __forceinline__ ushort4 pk4(float4 v) {
    return make_ushort4(f2b(v.x), f2b(v.y), f2b(v.z), f2b(v.w));
}

// ---------------- lin0: h0 = relu(x @ W + b)  --  MFMA bf16 GEMM ----------------
__global__ __launch_bounds__(256) void lin0_kernel(const float* __restrict__ x,
    const float* __restrict__ w, const float* __restrict__ b,
    unsigned short* __restrict__ h0)
{
    __shared__ unsigned short as_[128][40];  // A tile bf16 [m][k], rows padded 32->40
    __shared__ unsigned short wt[64][40];    // W^T chunk bf16 [n][k]
    const int tid = threadIdx.x;
    const int wv = tid >> 6, lane = tid & 63;
    const int ln15 = lane & 15, q = lane >> 4;
    const int m0 = blockIdx.x * 128;

    floatx4 acc[2][4];
#pragma unroll
    for (int i = 0; i < 2; ++i)
#pragma unroll
        for (int t = 0; t < 4; ++t) acc[i][t] = (floatx4){0.f, 0.f, 0.f, 0.f};

    const int r_ = tid >> 1, hh = tid & 1;       // staging: row, 16-float half
    int gms = m0 + r_; if (gms >= NNODES) gms = NNODES - 1;
    const float* xrow = x + (size_t)gms * NFEAT;

    for (int c = 0; c < 16; ++c) {
        const int k0 = c * 32;
        // ---- stage A: 128 x 32 fp32 -> bf16 ----
        {
            float4 v0, v1, v2, v3;
            if (c < 15 || hh == 0) {
                const float4* p4 = (const float4*)(xrow + k0 + 16 * hh);
                v0 = p4[0]; v1 = p4[1]; v2 = p4[2]; v3 = p4[3];
            } else {  // tail: k 496..511, only 496..499 valid
                v0 = *(const float4*)(xrow + 496);
                v1 = make_float4(0, 0, 0, 0); v2 = v1; v3 = v1;
            }
            ushort4* dst4 = (ushort4*)&as_[r_][16 * hh];
            dst4[0] = pk4(v0); dst4[1] = pk4(v1); dst4[2] = pk4(v2); dst4[3] = pk4(v3);
        }
        // ---- stage W^T: 32 x 64 fp32 -> bf16 [n][k] ----
#pragma unroll
        for (int ii = 0; ii < 2; ++ii) {
            int i = tid + ii * 256;               // float4 index in chunk (512 total)
            int k = i >> 4, nb = (i & 15) * 4;
            float4 v = make_float4(0, 0, 0, 0);
            if (c < 15 || i < 320)                // k0+k < 500
                v = ((const float4*)(w + (size_t)k0 * HID))[i];
            wt[nb + 0][k] = f2b(v.x); wt[nb + 1][k] = f2b(v.y);
            wt[nb + 2][k] = f2b(v.z); wt[nb + 3][k] = f2b(v.w);
        }
        __syncthreads();
        // ---- frags + MFMA ----
        short8 af[2], bfr[4];
#pragma unroll
        for (int mt = 0; mt < 2; ++mt)
            af[mt] = *(const short8*)&as_[32 * wv + 16 * mt + ln15][8 * q];
#pragma unroll
        for (int t = 0; t < 4; ++t)
            bfr[t] = *(const short8*)&wt[16 * t + ln15][8 * q];
#pragma unroll
        for (int mt = 0; mt < 2; ++mt)
#pragma unroll
            for (int t = 0; t < 4; ++t)
                acc[mt][t] = __builtin_amdgcn_mfma_f32_16x16x32_bf16(
                    af[mt], bfr[t], acc[mt][t], 0, 0, 0);
        __syncthreads();
    }
    // ---- epilogue: C/D layout col=lane&15, row=q*4+reg ----
    float bv[4];
#pragma unroll
    for (int t = 0; t < 4; ++t) bv[t] = b[16 * t + ln15];
#pragma unroll
    for (int mt = 0; mt < 2; ++mt)
#pragma unroll
        for (int r = 0; r < 4; ++r) {
            int gm = m0 + 32 * wv + 16 * mt + q * 4 + r;
            if (gm < NNODES) {
#pragma unroll
                for (int t = 0; t < 4; ++t)
                    h0[(size_t)gm * HID + 16 * t + ln15] =
                        f2b(fmaxf(acc[mt][t][r] + bv[t], 0.f));
            }
        }
}

// ============ two-level CSR build ============
// Level A: partition edges into 64 contiguous dst-range bins. Block-local LDS
// histogram -> one global atomicAdd per (block,bin) reserves a contiguous
// chunk -> writes land in small hot per-block regions (lines fill fast, no
// 9x write amplification, no hot global cursors).
// Level B: count/scan/scatter operate bin-locally: per-bin cursor slice 100KB,
// srcw write window 400KB -> L2-resident, dirty lines fill before eviction.
// Entry packing: (dst_local<<17)|src (11+17 bits), weight in .y.

__global__ __launch_bounds__(256) void bin_count_kernel(const int* __restrict__ dst,
                                                        int* __restrict__ bin_tot)
{
    __shared__ int h[NBIN];
    if (threadIdx.x < NBIN) h[threadIdx.x] = 0;
    __syncthreads();
    const int eb = blockIdx.x * 2048;
#pragma unroll
    for (int i = 0; i < 8; ++i) {
        int e = eb + i * 256 + threadIdx.x;
        if (e < NEDGES) {
            int d = __builtin_nontemporal_load(dst + e);
            atomicAdd(&h[d / NODES_PER_BIN], 1);
        }
    }
    __syncthreads();
    if (threadIdx.x < NBIN && h[threadIdx.x])
        atomicAdd(&bin_tot[threadIdx.x], h[threadIdx.x]);
}

__global__ void bin_scan_kernel(const int* __restrict__ bin_tot,
                                int* __restrict__ bin_base, int* __restrict__ bin_cur)
{
    const int t = threadIdx.x;         // 64 threads
    const int c = bin_tot[t];
    int v = c;
#pragma unroll
    for (int off = 1; off < 64; off <<= 1) {
        int u = __shfl_up(v, off, 64);
        if (t >= off) v += u;
    }
    bin_base[t] = v - c;               // exclusive prefix
    bin_cur[t]  = v - c;
    if (t == 63) bin_base[64] = v;     // grand total (= NEDGES)
}

__global__ __launch_bounds__(256) void bin_scatter_kernel(const int* __restrict__ src,
    const int* __restrict__ dst, const float* __restrict__ w,
    int* __restrict__ bin_cur, int2* __restrict__ bsrcw)
{
    __shared__ int h[NBIN], base[NBIN];
    if (threadIdx.x < NBIN) h[threadIdx.x] = 0;
    __syncthreads();
    const int eb = blockIdx.x * 2048;
    int dv[8], sv[8], bv[8]; float wv[8];
#pragma unroll
    for (int i = 0; i < 8; ++i) {
        int e = eb + i * 256 + threadIdx.x;
        if (e < NEDGES) {
            dv[i] = __builtin_nontemporal_load(dst + e);
            sv[i] = __builtin_nontemporal_load(src + e);
            wv[i] = __builtin_nontemporal_load(w + e);
            bv[i] = dv[i] / NODES_PER_BIN;
            atomicAdd(&h[bv[i]], 1);
        } else dv[i] = -1;
    }
    __syncthreads();
    if (threadIdx.x < NBIN) {
        int c = h[threadIdx.x];
        base[threadIdx.x] = c ? atomicAdd(&bin_cur[threadIdx.x], c) : 0;
        h[threadIdx.x] = 0;
    }
    __syncthreads();
#pragma unroll
    for (int i = 0; i < 8; ++i) {
        if (dv[i] >= 0) {
            int r = atomicAdd(&h[bv[i]], 1);
            int dl = dv[i] - bv[i] * NODES_PER_BIN;
            bsrcw[base[bv[i]] + r] = make_int2((dl << 17) | sv[i], __float_as_int(wv[i]));
        }
    }
}

// position->bin via 6-step binary search over bin_base (in LDS)
static __device__ __forceinline__ int find_bin(const int* bb, int e) {
    int lo = 0, hi = NBIN;
    while (hi - lo > 1) { int mid = (lo + hi) >> 1; if (e >= bb[mid]) lo = mid; else hi = mid; }
    return lo;
}

__global__ __launch_bounds__(256) void count_kernel(const int2* __restrict__ bsrcw,
    const int* __restrict__ bin_base, int* __restrict__ degb)
{
    __shared__ int bb[NBIN + 1];
    if (threadIdx.x <= NBIN) bb[threadIdx.x] = bin_base[threadIdx.x];
    __syncthreads();
    const int e = blockIdx.x * 256 + threadIdx.x;
    const int bin = find_bin(bb, e);
    const int2 p = bsrcw[e];
    const int s = p.x & 0x1FFFF;
    const int d = bin * NODES_PER_BIN + (((unsigned)p.x) >> 17);
    atomicAdd(&degb[d * NBUCK + s / NODES_PER_BUCK], 1);
}

__global__ __launch_bounds__(1024) void chunk_sum_kernel(const int* __restrict__ degb,
                                                         int* __restrict__ csum)
{
    __shared__ int sm[1024];
    int i = blockIdx.x * 1024 + threadIdx.x;
    int v = 0;
    if (i < NNODES) {
        const int4* q = (const int4*)(degb + (size_t)i * NBUCK);
        int4 a = q[0], b = q[1], c = q[2], d = q[3];
        v = a.x + a.y + a.z + a.w + b.x + b.y + b.z + b.w
          + c.x + c.y + c.z + c.w + d.x + d.y + d.z + d.w;
        v = (v + 3) & ~3;
    }
    sm[threadIdx.x] = v;
    __syncthreads();
    for (int off = 512; off > 0; off >>= 1) {
        if (threadIdx.x < off) sm[threadIdx.x] += sm[threadIdx.x + off];
        __syncthreads();
    }
    if (threadIdx.x == 0) csum[blockIdx.x] = sm[0];
}

__global__ __launch_bounds__(128) void chunk_base_kernel(const int* __restrict__ csum,
    int* __restrict__ cbase, int* __restrict__ offs, int nchunks)
{
    __shared__ int s[128];
    const int t = threadIdx.x;
    int v = (t < nchunks) ? csum[t] : 0;
    s[t] = v;
    __syncthreads();
    for (int off = 1; off < 128; off <<= 1) {
        int u = (t >= off) ? s[t - off] : 0;
        __syncthreads();
        s[t] += u;
        __syncthreads();
    }
    if (t < nchunks) cbase[t] = s[t] - v;          // exclusive prefix
    if (t == nchunks - 1) offs[NNODES] = s[t];     // grand total
}

__global__ __launch_bounds__(1024) void scan_kernel(const int* __restrict__ degb,
    const int* __restrict__ cbase, int* __restrict__ offs, int* __restrict__ cur)
{
    __shared__ int sm[1024];
    int i = blockIdx.x * 1024 + threadIdx.x;
    int dv[16];
    int v = 0;
    if (i < NNODES) {
        const int4* q = (const int4*)(degb + (size_t)i * NBUCK);
#pragma unroll
        for (int j = 0; j < 4; ++j) {
            int4 a = q[j];
            dv[4 * j + 0] = a.x; dv[4 * j + 1] = a.y;
            dv[4 * j + 2] = a.z; dv[4 * j + 3] = a.w;
            v += a.x + a.y + a.z + a.w;
        }
        v = (v + 3) & ~3;
    }
    sm[threadIdx.x] = v;
    __syncthreads();
    for (int off = 1; off < 1024; off <<= 1) {
        int t = (threadIdx.x >= off) ? sm[threadIdx.x - off] : 0;
        __syncthreads();
        sm[threadIdx.x] += t;
        __syncthreads();
    }
    if (i < NNODES) {
        int excl = cbase[blockIdx.x] + sm[threadIdx.x] - v;
        offs[i] = excl;
        int run = excl;
#pragma unroll
        for (int b = 0; b < NBUCK; ++b) {   // per-bucket sub-cursor bases
            cur[(size_t)i * NBUCK + b] = run;
            run += dv[b];
        }
    }
}

__global__ __launch_bounds__(256) void scatter_kernel(const int2* __restrict__ bsrcw,
    const int* __restrict__ bin_base, int* __restrict__ cur, int2* __restrict__ srcw)
{
    __shared__ int bb[NBIN + 1];
    if (threadIdx.x <= NBIN) bb[threadIdx.x] = bin_base[threadIdx.x];
    __syncthreads();
    const int e = blockIdx.x * 256 + threadIdx.x;
    const int bin = find_bin(bb, e);
    const int2 p = bsrcw[e];
    const int s = p.x & 0x1FFFF;
    const int d = bin * NODES_PER_BIN + (((unsigned)p.x) >> 17);
    int pos = atomicAdd(&cur[d * NBUCK + s / NODES_PER_BUCK], 1);
    srcw[pos] = make_int2(s * 128, p.y);  // byte offset, weight
}

__global__ __launch_bounds__(256) void pad_kernel(const int* __restrict__ offs,
    const int* __restrict__ cur, int2* __restrict__ srcw)
{
    int n = blockIdx.x * 256 + threadIdx.x;
    if (n < NNODES) {
        int e = cur[(size_t)n * NBUCK + NBUCK - 1];  // post-scatter = offs[n]+deg[n]
        int e1 = offs[n + 1];
        for (; e < e1; ++e) srcw[e] = make_int2(0, 0);
    }
}

// ---------------- fused SpMM + blend + dense + relu layer ----------------
// Gather: QUARTER-wave per node (4 nodes/wave), uint2 (8B)/lane, 4 edges/iter
//   (deg padded x4). Edge lists src-bucket-ordered -> concurrent waves sweep
//   the same ~0.8MB h-window. Plain (cached) loads: srcw/x0 are re-read every
//   layer and live in L3 (round-4 NT experiment: bypassing L3 cost 14us/layer).
// Dense: MFMA 16x16x32 bf16.
__global__ __launch_bounds__(256) void spmm_layer_kernel(
    const unsigned short* __restrict__ h_in, const unsigned short* __restrict__ x0,
    unsigned short* __restrict__ h_out, const int* __restrict__ offs,
    const int2* __restrict__ srcw, const float* __restrict__ Wg, float beta)
{
    __shared__ float          zs [NPB][72];  // f32 z (residual term)
    __shared__ unsigned short zsb[NPB][72];  // bf16 z (MFMA A operand)
    __shared__ unsigned short WbT[HID][72];  // bf16 W^T: WbT[j][k] = Wg[k][j]
    const int tid = threadIdx.x;

    // ---- stage WbT (fp32 -> bf16, transposed) ----
    for (int i = tid; i < 1024; i += 256) {
        float4 v = ((const float4*)Wg)[i];
        int k = i >> 4, j = (i & 15) * 4;
        WbT[j + 0][k] = f2b(v.x); WbT[j + 1][k] = f2b(v.y);
        WbT[j + 2][k] = f2b(v.z); WbT[j + 3][k] = f2b(v.w);
    }

    const int wv = tid >> 6, lane = tid & 63;
    const int qt = lane >> 4, ln = lane & 15;   // quarter id, lane-in-quarter
    const int nloc = wv * 4 + qt;               // local node 0..15
    const int n = blockIdx.x * NPB + nloc;
    int e = offs[n];
    const int e1 = offs[n + 1];
    const char* hbl = (const char*)h_in + ln * 8;
    float a0 = 0.f, a1 = 0.f, a2 = 0.f, a3 = 0.f;
    for (; e < e1; e += 4) {        // deg padded to multiple of 4
        int4 p0 = *(const int4*)(srcw + e);          // edges 0,1
        int4 p1 = *(const int4*)(srcw + e + 2);      // edges 2,3
        uint2 v0 = *(const uint2*)(hbl + p0.x);
        uint2 v1 = *(const uint2*)(hbl + p0.z);
        uint2 v2 = *(const uint2*)(hbl + p1.x);
        uint2 v3 = *(const uint2*)(hbl + p1.z);
        float w0 = __int_as_float(p0.y), w1 = __int_as_float(p0.w);
        float w2 = __int_as_float(p1.y), w3 = __int_as_float(p1.w);
        a0 = fmaf(w0, __uint_as_float(v0.x << 16), a0);
        a1 = fmaf(w0, __uint_as_float(v0.x & 0xffff0000u), a1);
        a2 = fmaf(w0, __uint_as_float(v0.y << 16), a2);
        a3 = fmaf(w0, __uint_as_float(v0.y & 0xffff0000u), a3);
        a0 = fmaf(w1, __uint_as_float(v1.x << 16), a0);
        a1 = fmaf(w1, __uint_as_float(v1.x & 0xffff0000u), a1);
        a2 = fmaf(w1, __uint_as_float(v1.y << 16), a2);
        a3 = fmaf(w1, __uint_as_float(v1.y & 0xffff0000u), a3);
        a0 = fmaf(w2, __uint_as_float(v2.x << 16), a0);
        a1 = fmaf(w2, __uint_as_float(v2.x & 0xffff0000u), a1);
        a2 = fmaf(w2, __uint_as_float(v2.y << 16), a2);
        a3 = fmaf(w2, __uint_as_float(v2.y & 0xffff0000u), a3);
        a0 = fmaf(w3, __uint_as_float(v3.x << 16), a0);
        a1 = fmaf(w3, __uint_as_float(v3.x & 0xffff0000u), a1);
        a2 = fmaf(w3, __uint_as_float(v3.y << 16), a2);
        a3 = fmaf(w3, __uint_as_float(v3.y & 0xffff0000u), a3);
    }
    // blend with initial residual x0 (bf16), write f32 + bf16 copies of z
    uint2 xv = *(const uint2*)((const char*)x0 + (size_t)n * 128 + ln * 8);
    float z0 = 0.9f * a0 + 0.1f * __uint_as_float(xv.x << 16);
    float z1 = 0.9f * a1 + 0.1f * __uint_as_float(xv.x & 0xffff0000u);
    float z2 = 0.9f * a2 + 0.1f * __uint_as_float(xv.y << 16);
    float z3 = 0.9f * a3 + 0.1f * __uint_as_float(xv.y & 0xffff0000u);
    *(float4*)&zs[nloc][4 * ln] = make_float4(z0, z1, z2, z3);
    *(ushort4*)&zsb[nloc][4 * ln] = make_ushort4(f2b(z0), f2b(z1), f2b(z2), f2b(z3));
    __syncthreads();

    // ---- dense phase: mm = z @ W via MFMA. wave wv owns N-tile cols 16wv..16wv+15.
    floatx4 acc = (floatx4){0.f, 0.f, 0.f, 0.f};
#pragma unroll
    for (int s = 0; s < 2; ++s) {
        short8 af = *(const short8*)&zsb[ln][32 * s + 8 * qt];
        short8 bf = *(const short8*)&WbT[16 * wv + ln][32 * s + 8 * qt];
        acc = __builtin_amdgcn_mfma_f32_16x16x32_bf16(af, bf, acc, 0, 0, 0);
    }
    // C layout: col = lane&15 (j in tile), row = qt*4 + reg  -> row = node
    const float ob = 1.f - beta;
    const size_t base = (size_t)blockIdx.x * NPB;
#pragma unroll
    for (int r4 = 0; r4 < 4; ++r4) {
        const int node = qt * 4 + r4;
        const int j = 16 * wv + ln;
        float hv = fmaxf(ob * zs[node][j] + beta * acc[r4], 0.f);
        h_out[(base + node) * HID + j] = f2b(hv);
    }
}

// ---------------- final: log_softmax(h @ W1 + b1) ----------------
__global__ __launch_bounds__(256) void final_kernel(const unsigned short* __restrict__ h,
    const float* __restrict__ w1, const float* __restrict__ b1, float* __restrict__ out)
{
    const int m = threadIdx.x >> 6, j = threadIdx.x & 63;
    const long n = (long)blockIdx.x * 4 + m;
    const int jj = (j < NCLS) ? j : NCLS - 1;
    const ushort4* hrow = (const ushort4*)(h + n * HID);
    float acc = b1[jj];
#pragma unroll
    for (int k4 = 0; k4 < 16; ++k4) {
        ushort4 hv = hrow[k4];
        const int k = k4 * 4;
        acc = fmaf(b2f(hv.x), w1[(k + 0) * NCLS + jj], acc);
        acc = fmaf(b2f(hv.y), w1[(k + 1) * NCLS + jj], acc);
        acc = fmaf(b2f(hv.z), w1[(k + 2) * NCLS + jj], acc);
        acc = fmaf(b2f(hv.w), w1[(k + 3) * NCLS + jj], acc);
    }
    float lg = (j < NCLS) ? acc : -INFINITY;
    float mx = lg;
#pragma unroll
    for (int o = 32; o > 0; o >>= 1) mx = fmaxf(mx, __shfl_xor(mx, o, 64));
    float ex = (j < NCLS) ? expf(acc - mx) : 0.f;
    float sm = ex;
#pragma unroll
    for (int o = 32; o > 0; o >>= 1) sm += __shfl_xor(sm, o, 64);
    if (j < NCLS) out[n * NCLS + j] = acc - mx - logf(sm);
}

extern "C" void kernel_launch(void* const* d_in, const int* in_sizes, int n_in,
                              void* d_out, int out_size, void* d_ws, size_t ws_size,
                              hipStream_t stream)
{
    const float* x    = (const float*)d_in[0];
    const int*   esrc = (const int*)d_in[1];
    const int*   edst = (const int*)d_in[2];
    const float* ew   = (const float*)d_in[3];
    const float* l0w  = (const float*)d_in[4];
    const float* l0b  = (const float*)d_in[5];
    const float* cw   = (const float*)d_in[6];
    const float* l1w  = (const float*)d_in[7];
    const float* l1b  = (const float*)d_in[8];
    float* out = (float*)d_out;

    char* p = (char*)d_ws;
    unsigned short* h0 = (unsigned short*)p; p += (size_t)NNODES * HID * 2;  // 12.8MB
    unsigned short* hA = (unsigned short*)p; p += (size_t)NNODES * HID * 2;
    unsigned short* hB = (unsigned short*)p; p += (size_t)NNODES * HID * 2;
    int2*  srcw = (int2*)p;  p += ((size_t)NEDGES + 4 * NNODES) * 8;  // padded CSR
    int* offs     = (int*)p; p += (size_t)(NNODES + 1) * 4;
    int* csum     = (int*)p; p += 512;
    int* cbase    = (int*)p; p += 512;
    int* bin_tot  = (int*)p; p += 256;
    int* bin_base = (int*)p; p += 512;   // 65 ints
    int* bin_cur  = (int*)p; p += 256;
    // Aliases (build runs BEFORE lin0/layers, all stream-ordered):
    //   bsrcw (3.2M int2 = 25.6MB) = h0+hA region (dead until lin0 writes h0,
    //     layer-0 writes hA); degb/cur (6.4MB each) = hB halves (dead until
    //     layer-1 writes hB).
    int2* bsrcw = (int2*)h0;
    int* degb = (int*)hB;
    int* cur  = (int*)((char*)hB + (size_t)NNODES * NBUCK * 4);

    const int nchunks = (NNODES + 1023) / 1024;   // 98

    hipMemsetAsync(bin_tot, 0, NBIN * sizeof(int), stream);
    hipMemsetAsync(degb, 0, (size_t)NNODES * NBUCK * sizeof(int), stream);

    const int nbb = (NEDGES + 2047) / 2048;       // 1563
    bin_count_kernel<<<nbb, 256, 0, stream>>>(edst, bin_tot);
    bin_scan_kernel<<<1, 64, 0, stream>>>(bin_tot, bin_base, bin_cur);
    bin_scatter_kernel<<<nbb, 256, 0, stream>>>(esrc, edst, ew, bin_cur, bsrcw);
    count_kernel<<<NEDGES / 256, 256, 0, stream>>>(bsrcw, bin_base, degb);
    chunk_sum_kernel<<<nchunks, 1024, 0, stream>>>(degb, csum);
    chunk_base_kernel<<<1, 128, 0, stream>>>(csum, cbase, offs, nchunks);
    scan_kernel<<<nchunks, 1024, 0, stream>>>(degb, cbase, offs, cur);
    scatter_kernel<<<NEDGES / 256, 256, 0, stream>>>(bsrcw, bin_base, cur, srcw);
    pad_kernel<<<(NNODES + 255) / 256, 256, 0, stream>>>(offs, cur, srcw);

    // lin0 AFTER the build: h0 region doubles as bsrcw during the build.
    lin0_kernel<<<(NNODES + 127) / 128, 256, 0, stream>>>(x, l0w, l0b, h0);

    const unsigned short* hin = h0;
    unsigned short* bufs[2] = { hA, hB };
    for (int l = 0; l < NLAYERS; ++l) {
        float beta = (float)log(0.5 / (double)(l + 1) + 1.0);
        unsigned short* hout = bufs[l & 1];
        spmm_layer_kernel<<<NNODES / NPB, 256, 0, stream>>>(
            hin, h0, hout, offs, srcw, cw + (size_t)l * HID * HID, beta);
        hin = hout;
    }
    final_kernel<<<NNODES / 4, 256, 0, stream>>>(hin, l1w, l1b, out);
}

// Round 7
// 1036.639 us; speedup vs baseline: 1.2866x; 1.2866x over previous
//
#include <hip/hip_runtime.h>
#include <math.h>

#define NNODES 100000
#define NEDGES 3200000
#define NFEAT  500
#define HID    64
#define NCLS   40
#define NLAYERS 8
#define NPB    16      // spmm nodes per block (quarter-wave gather: 4 nodes/wave)
#define NBUCK  16      // src-range buckets per node list (6250 nodes = 0.8MB bf16 rows)
#define NODES_PER_BUCK 6250
#define NBIN   256     // dst-range bins; one block per bin does the final sort
#define NPBIN  391     // nodes per bin (last bin: 295)
#define NKEY   (NPBIN * NBUCK)   // 6256 (node,bucket) keys per bin
#define DEGB_STRIDE 6272
#define NBASE_STRIDE 392

typedef __attribute__((ext_vector_type(8))) short short8;   // 8 bf16 (4 VGPRs)
typedef __attribute__((ext_vector_type(4))) float floatx4;  // MFMA acc

static __device__ __forceinline__ float b2f(unsigned short u) {
    return __uint_as_float(((unsigned)u) << 16);
}
static __device__ __forceinline__ unsigned short f2b(float f) {
    unsigned u = __float_as_uint(f);
    return (unsigned short)((u + 0x7FFFu + ((u >> 16) & 1u)) >> 16);  // RNE
}
static __device__ __forceinline__ ushort4 pk4(float4 v) {
    return make_ushort4(f2b(v.x), f2b(v.y), f2b(v.z), f2b(v.w));
}

// ---------------- lin0: h0 = relu(x @ W + b)  --  MFMA bf16 GEMM ----------------
__global__ __launch_bounds__(256) void lin0_kernel(const float* __restrict__ x,
    const float* __restrict__ w, const float* __restrict__ b,
    unsigned short* __restrict__ h0)
{
    __shared__ unsigned short as_[128][40];  // A tile bf16 [m][k], rows padded 32->40
    __shared__ unsigned short wt[64][40];    // W^T chunk bf16 [n][k]
    const int tid = threadIdx.x;
    const int wv = tid >> 6, lane = tid & 63;
    const int ln15 = lane & 15, q = lane >> 4;
    const int m0 = blockIdx.x * 128;

    floatx4 acc[2][4];
#pragma unroll
    for (int i = 0; i < 2; ++i)
#pragma unroll
        for (int t = 0; t < 4; ++t) acc[i][t] = (floatx4){0.f, 0.f, 0.f, 0.f};

    const int r_ = tid >> 1, hh = tid & 1;       // staging: row, 16-float half
    int gms = m0 + r_; if (gms >= NNODES) gms = NNODES - 1;
    const float* xrow = x + (size_t)gms * NFEAT;

    for (int c = 0; c < 16; ++c) {
        const int k0 = c * 32;
        // ---- stage A: 128 x 32 fp32 -> bf16 ----
        {
            float4 v0, v1, v2, v3;
            if (c < 15 || hh == 0) {
                const float4* p4 = (const float4*)(xrow + k0 + 16 * hh);
                v0 = p4[0]; v1 = p4[1]; v2 = p4[2]; v3 = p4[3];
            } else {  // tail: k 496..511, only 496..499 valid
                v0 = *(const float4*)(xrow + 496);
                v1 = make_float4(0, 0, 0, 0); v2 = v1; v3 = v1;
            }
            ushort4* dst4 = (ushort4*)&as_[r_][16 * hh];
            dst4[0] = pk4(v0); dst4[1] = pk4(v1); dst4[2] = pk4(v2); dst4[3] = pk4(v3);
        }
        // ---- stage W^T: 32 x 64 fp32 -> bf16 [n][k] ----
#pragma unroll
        for (int ii = 0; ii < 2; ++ii) {
            int i = tid + ii * 256;               // float4 index in chunk (512 total)
            int k = i >> 4, nb = (i & 15) * 4;
            float4 v = make_float4(0, 0, 0, 0);
            if (c < 15 || i < 320)                // k0+k < 500
                v = ((const float4*)(w + (size_t)k0 * HID))[i];
            wt[nb + 0][k] = f2b(v.x); wt[nb + 1][k] = f2b(v.y);
            wt[nb + 2][k] = f2b(v.z); wt[nb + 3][k] = f2b(v.w);
        }
        __syncthreads();
        // ---- frags + MFMA ----
        short8 af[2], bfr[4];
#pragma unroll
        for (int mt = 0; mt < 2; ++mt)
            af[mt] = *(const short8*)&as_[32 * wv + 16 * mt + ln15][8 * q];
#pragma unroll
        for (int t = 0; t < 4; ++t)
            bfr[t] = *(const short8*)&wt[16 * t + ln15][8 * q];
#pragma unroll
        for (int mt = 0; mt < 2; ++mt)
#pragma unroll
            for (int t = 0; t < 4; ++t)
                acc[mt][t] = __builtin_amdgcn_mfma_f32_16x16x32_bf16(
                    af[mt], bfr[t], acc[mt][t], 0, 0, 0);
        __syncthreads();
    }
    // ---- epilogue: C/D layout col=lane&15, row=q*4+reg ----
    float bv[4];
#pragma unroll
    for (int t = 0; t < 4; ++t) bv[t] = b[16 * t + ln15];
#pragma unroll
    for (int mt = 0; mt < 2; ++mt)
#pragma unroll
        for (int r = 0; r < 4; ++r) {
            int gm = m0 + 32 * wv + 16 * mt + q * 4 + r;
            if (gm < NNODES) {
#pragma unroll
                for (int t = 0; t < 4; ++t)
                    h0[(size_t)gm * HID + 16 * t + ln15] =
                        f2b(fmaxf(acc[mt][t][r] + bv[t], 0.f));
            }
        }
}

// ============ CSR build via single-writer-XCD LDS counting sort ============
// Round-6 lesson: any dirty window written by blocks on multiple XCDs
// ping-pongs L2 lines -> 9x write amplification + 2us atomic latency.
// Invariant here: every randomly-written region has a SINGLE writing block.
//   Pass 1: edges -> 256 dst-range bins (block-chunk reservation: ~8 edges
//           = one 64B line per (block,bin) chunk -> line-dense writes).
//   Pass 2: one block per bin: LDS histogram of (node,bucket) keys, padded
//           block scan -> per-node offsets, LDS-atomic rank, write srcw.
//           The bin's 100KB output window is written by ONE CU only.
// Entry packing: (dst_local<<17)|src  (dl<391 -> 9 bits; src<2^17).

__global__ __launch_bounds__(256) void bin_count_kernel(const int* __restrict__ dst,
                                                        int* __restrict__ bin_tot)
{
    __shared__ int h[NBIN];
    h[threadIdx.x] = 0;
    __syncthreads();
    const int eb = blockIdx.x * 2048;
#pragma unroll
    for (int i = 0; i < 8; ++i) {
        int e = eb + i * 256 + threadIdx.x;
        if (e < NEDGES) {
            int d = __builtin_nontemporal_load(dst + e);
            atomicAdd(&h[d / NPBIN], 1);
        }
    }
    __syncthreads();
    if (h[threadIdx.x]) atomicAdd(&bin_tot[threadIdx.x], h[threadIdx.x]);
}

__global__ void bin_scan_kernel(const int* __restrict__ bin_tot,
                                int* __restrict__ bin_base, int* __restrict__ bin_cur)
{
    __shared__ int s[NBIN];
    const int t = threadIdx.x;        // 256 threads
    const int c = bin_tot[t];
    s[t] = c;
    __syncthreads();
    for (int off = 1; off < NBIN; off <<= 1) {
        int u = (t >= off) ? s[t - off] : 0;
        __syncthreads();
        s[t] += u;
        __syncthreads();
    }
    bin_base[t] = s[t] - c;
    bin_cur[t]  = s[t] - c;
    if (t == NBIN - 1) bin_base[NBIN] = s[t];    // = NEDGES
}

__global__ __launch_bounds__(256) void bin_scatter_kernel(const int* __restrict__ src,
    const int* __restrict__ dst, const float* __restrict__ w,
    int* __restrict__ bin_cur, int2* __restrict__ bsrcw)
{
    __shared__ int h[NBIN], base[NBIN];
    h[threadIdx.x] = 0;
    __syncthreads();
    const int eb = blockIdx.x * 2048;
    int dv[8], sv[8], bv[8]; float wv[8];
#pragma unroll
    for (int i = 0; i < 8; ++i) {
        int e = eb + i * 256 + threadIdx.x;
        if (e < NEDGES) {
            dv[i] = __builtin_nontemporal_load(dst + e);
            sv[i] = __builtin_nontemporal_load(src + e);
            wv[i] = __builtin_nontemporal_load(w + e);
            bv[i] = dv[i] / NPBIN;
            atomicAdd(&h[bv[i]], 1);
        } else dv[i] = -1;
    }
    __syncthreads();
    {
        int c = h[threadIdx.x];
        base[threadIdx.x] = c ? atomicAdd(&bin_cur[threadIdx.x], c) : 0;
        h[threadIdx.x] = 0;
    }
    __syncthreads();
#pragma unroll
    for (int i = 0; i < 8; ++i) {
        if (dv[i] >= 0) {
            int r = atomicAdd(&h[bv[i]], 1);
            int dl = dv[i] - bv[i] * NPBIN;
            bsrcw[base[bv[i]] + r] = make_int2((dl << 17) | sv[i], __float_as_int(wv[i]));
        }
    }
}

// one block per bin: key histogram + padded node scan; dumps cnt + node bases
__global__ __launch_bounds__(512) void bin_hist_kernel(const int2* __restrict__ bsrcw,
    const int* __restrict__ bin_base, int* __restrict__ degb_g,
    int* __restrict__ nbase_g, int* __restrict__ bpad)
{
    __shared__ int cnt[NKEY];
    __shared__ int nb[512];
    const int b = blockIdx.x, t = threadIdx.x;
    const int nn = min(NPBIN, NNODES - b * NPBIN);
    for (int k = t; k < NKEY; k += 512) cnt[k] = 0;
    __syncthreads();
    const int e0 = bin_base[b], e1 = bin_base[b + 1];
    for (int e = e0 + t; e < e1; e += 512) {
        int px = bsrcw[e].x;
        int key = (int)(((unsigned)px) >> 17) * NBUCK + (px & 0x1FFFF) / NODES_PER_BUCK;
        atomicAdd(&cnt[key], 1);
    }
    __syncthreads();
    int pdeg = 0;
    if (t < nn) {
        int run = 0;
#pragma unroll
        for (int k = 0; k < NBUCK; ++k) run += cnt[t * NBUCK + k];
        pdeg = (run + 3) & ~3;
    }
    nb[t] = pdeg;
    __syncthreads();
    for (int off = 1; off < 512; off <<= 1) {
        int u = (t >= off) ? nb[t - off] : 0;
        __syncthreads();
        nb[t] += u;
        __syncthreads();
    }
    if (t < nn) nbase_g[b * NBASE_STRIDE + t] = nb[t] - pdeg;
    if (t == nn - 1) {
        nbase_g[b * NBASE_STRIDE + nn] = nb[t];
        bpad[b] = nb[t];
    }
    for (int k = t; k < NKEY; k += 512) degb_g[(size_t)b * DEGB_STRIDE + k] = cnt[k];
}

__global__ void pbase_scan_kernel(const int* __restrict__ bpad,
                                  int* __restrict__ pbase, int* __restrict__ offs)
{
    __shared__ int s[NBIN];
    const int t = threadIdx.x;
    const int c = bpad[t];
    s[t] = c;
    __syncthreads();
    for (int off = 1; off < NBIN; off <<= 1) {
        int u = (t >= off) ? s[t - off] : 0;
        __syncthreads();
        s[t] += u;
        __syncthreads();
    }
    pbase[t] = s[t] - c;
    if (t == NBIN - 1) { pbase[NBIN] = s[t]; offs[NNODES] = s[t]; }
}

// one block per bin: rank via LDS atomics, write srcw + pads + offs
__global__ __launch_bounds__(512) void bin_write_kernel(const int2* __restrict__ bsrcw,
    const int* __restrict__ bin_base, const int* __restrict__ degb_g,
    const int* __restrict__ nbase_g, const int* __restrict__ pbase,
    int2* __restrict__ srcw, int* __restrict__ offs)
{
    __shared__ int kb[NKEY];
    __shared__ int nbs[NPBIN + 1];
    const int b = blockIdx.x, t = threadIdx.x;
    const int nn = min(NPBIN, NNODES - b * NPBIN);
    const int pb = pbase[b];
    for (int i = t; i <= nn; i += 512) nbs[i] = nbase_g[b * NBASE_STRIDE + i];
    __syncthreads();
    if (t < nn) {
        int run = nbs[t];
#pragma unroll
        for (int k = 0; k < NBUCK; ++k) {
            int c = degb_g[(size_t)b * DEGB_STRIDE + t * NBUCK + k];
            kb[t * NBUCK + k] = run;
            run += c;
        }
    }
    __syncthreads();
    const int e0 = bin_base[b], e1 = bin_base[b + 1];
    for (int e = e0 + t; e < e1; e += 512) {
        int2 p = bsrcw[e];
        int s = p.x & 0x1FFFF;
        int key = (int)(((unsigned)p.x) >> 17) * NBUCK + s / NODES_PER_BUCK;
        int pos = atomicAdd(&kb[key], 1);
        srcw[pb + pos] = make_int2(s * 128, p.y);   // byte offset, weight
    }
    __syncthreads();
    if (t < nn) {
        int e = kb[t * NBUCK + NBUCK - 1];          // = nbs[t] + deg[t]
        const int ep = nbs[t + 1];                  // = nbs[t] + padded deg
        for (; e < ep; ++e) srcw[pb + e] = make_int2(0, 0);
        offs[b * NPBIN + t] = pb + nbs[t];
    }
}

// ---------------- fused SpMM + blend + dense + relu layer ----------------
// Gather: QUARTER-wave per node (4 nodes/wave), uint2 (8B)/lane, 4 edges/iter
//   (deg padded x4). Edge lists src-bucket-ordered -> concurrent waves sweep
//   the same ~0.8MB h-window. Plain (cached) loads: srcw/x0 are re-read every
//   layer and live in L3 (round-4 NT experiment: bypassing L3 cost 14us/layer).
// Dense: MFMA 16x16x32 bf16.
__global__ __launch_bounds__(256) void spmm_layer_kernel(
    const unsigned short* __restrict__ h_in, const unsigned short* __restrict__ x0,
    unsigned short* __restrict__ h_out, const int* __restrict__ offs,
    const int2* __restrict__ srcw, const float* __restrict__ Wg, float beta)
{
    __shared__ float          zs [NPB][72];  // f32 z (residual term)
    __shared__ unsigned short zsb[NPB][72];  // bf16 z (MFMA A operand)
    __shared__ unsigned short WbT[HID][72];  // bf16 W^T: WbT[j][k] = Wg[k][j]
    const int tid = threadIdx.x;

    // ---- stage WbT (fp32 -> bf16, transposed) ----
    for (int i = tid; i < 1024; i += 256) {
        float4 v = ((const float4*)Wg)[i];
        int k = i >> 4, j = (i & 15) * 4;
        WbT[j + 0][k] = f2b(v.x); WbT[j + 1][k] = f2b(v.y);
        WbT[j + 2][k] = f2b(v.z); WbT[j + 3][k] = f2b(v.w);
    }

    const int wv = tid >> 6, lane = tid & 63;
    const int qt = lane >> 4, ln = lane & 15;   // quarter id, lane-in-quarter
    const int nloc = wv * 4 + qt;               // local node 0..15
    const int n = blockIdx.x * NPB + nloc;
    int e = offs[n];
    const int e1 = offs[n + 1];
    const char* hbl = (const char*)h_in + ln * 8;
    float a0 = 0.f, a1 = 0.f, a2 = 0.f, a3 = 0.f;
    for (; e < e1; e += 4) {        // deg padded to multiple of 4
        int4 p0 = *(const int4*)(srcw + e);          // edges 0,1
        int4 p1 = *(const int4*)(srcw + e + 2);      // edges 2,3
        uint2 v0 = *(const uint2*)(hbl + p0.x);
        uint2 v1 = *(const uint2*)(hbl + p0.z);
        uint2 v2 = *(const uint2*)(hbl + p1.x);
        uint2 v3 = *(const uint2*)(hbl + p1.z);
        float w0 = __int_as_float(p0.y), w1 = __int_as_float(p0.w);
        float w2 = __int_as_float(p1.y), w3 = __int_as_float(p1.w);
        a0 = fmaf(w0, __uint_as_float(v0.x << 16), a0);
        a1 = fmaf(w0, __uint_as_float(v0.x & 0xffff0000u), a1);
        a2 = fmaf(w0, __uint_as_float(v0.y << 16), a2);
        a3 = fmaf(w0, __uint_as_float(v0.y & 0xffff0000u), a3);
        a0 = fmaf(w1, __uint_as_float(v1.x << 16), a0);
        a1 = fmaf(w1, __uint_as_float(v1.x & 0xffff0000u), a1);
        a2 = fmaf(w1, __uint_as_float(v1.y << 16), a2);
        a3 = fmaf(w1, __uint_as_float(v1.y & 0xffff0000u), a3);
        a0 = fmaf(w2, __uint_as_float(v2.x << 16), a0);
        a1 = fmaf(w2, __uint_as_float(v2.x & 0xffff0000u), a1);
        a2 = fmaf(w2, __uint_as_float(v2.y << 16), a2);
        a3 = fmaf(w2, __uint_as_float(v2.y & 0xffff0000u), a3);
        a0 = fmaf(w3, __uint_as_float(v3.x << 16), a0);
        a1 = fmaf(w3, __uint_as_float(v3.x & 0xffff0000u), a1);
        a2 = fmaf(w3, __uint_as_float(v3.y << 16), a2);
        a3 = fmaf(w3, __uint_as_float(v3.y & 0xffff0000u), a3);
    }
    // blend with initial residual x0 (bf16), write f32 + bf16 copies of z
    uint2 xv = *(const uint2*)((const char*)x0 + (size_t)n * 128 + ln * 8);
    float z0 = 0.9f * a0 + 0.1f * __uint_as_float(xv.x << 16);
    float z1 = 0.9f * a1 + 0.1f * __uint_as_float(xv.x & 0xffff0000u);
    float z2 = 0.9f * a2 + 0.1f * __uint_as_float(xv.y << 16);
    float z3 = 0.9f * a3 + 0.1f * __uint_as_float(xv.y & 0xffff0000u);
    *(float4*)&zs[nloc][4 * ln] = make_float4(z0, z1, z2, z3);
    *(ushort4*)&zsb[nloc][4 * ln] = make_ushort4(f2b(z0), f2b(z1), f2b(z2), f2b(z3));
    __syncthreads();

    // ---- dense phase: mm = z @ W via MFMA. wave wv owns N-tile cols 16wv..16wv+15.
    floatx4 acc = (floatx4){0.f, 0.f, 0.f, 0.f};
#pragma unroll
    for (int s = 0; s < 2; ++s) {
        short8 af = *(const short8*)&zsb[ln][32 * s + 8 * qt];
        short8 bf = *(const short8*)&WbT[16 * wv + ln][32 * s + 8 * qt];
        acc = __builtin_amdgcn_mfma_f32_16x16x32_bf16(af, bf, acc, 0, 0, 0);
    }
    // C layout: col = lane&15 (j in tile), row = qt*4 + reg  -> row = node
    const float ob = 1.f - beta;
    const size_t base = (size_t)blockIdx.x * NPB;
#pragma unroll
    for (int r4 = 0; r4 < 4; ++r4) {
        const int node = qt * 4 + r4;
        const int j = 16 * wv + ln;
        float hv = fmaxf(ob * zs[node][j] + beta * acc[r4], 0.f);
        h_out[(base + node) * HID + j] = f2b(hv);
    }
}

// ---------------- final: log_softmax(h @ W1 + b1) ----------------
__global__ __launch_bounds__(256) void final_kernel(const unsigned short* __restrict__ h,
    const float* __restrict__ w1, const float* __restrict__ b1, float* __restrict__ out)
{
    const int m = threadIdx.x >> 6, j = threadIdx.x & 63;
    const long n = (long)blockIdx.x * 4 + m;
    const int jj = (j < NCLS) ? j : NCLS - 1;
    const ushort4* hrow = (const ushort4*)(h + n * HID);
    float acc = b1[jj];
#pragma unroll
    for (int k4 = 0; k4 < 16; ++k4) {
        ushort4 hv = hrow[k4];
        const int k = k4 * 4;
        acc = fmaf(b2f(hv.x), w1[(k + 0) * NCLS + jj], acc);
        acc = fmaf(b2f(hv.y), w1[(k + 1) * NCLS + jj], acc);
        acc = fmaf(b2f(hv.z), w1[(k + 2) * NCLS + jj], acc);
        acc = fmaf(b2f(hv.w), w1[(k + 3) * NCLS + jj], acc);
    }
    float lg = (j < NCLS) ? acc : -INFINITY;
    float mx = lg;
#pragma unroll
    for (int o = 32; o > 0; o >>= 1) mx = fmaxf(mx, __shfl_xor(mx, o, 64));
    float ex = (j < NCLS) ? expf(acc - mx) : 0.f;
    float sm = ex;
#pragma unroll
    for (int o = 32; o > 0; o >>= 1) sm += __shfl_xor(sm, o, 64);
    if (j < NCLS) out[n * NCLS + j] = acc - mx - logf(sm);
}

extern "C" void kernel_launch(void* const* d_in, const int* in_sizes, int n_in,
                              void* d_out, int out_size, void* d_ws, size_t ws_size,
                              hipStream_t stream)
{
    const float* x    = (const float*)d_in[0];
    const int*   esrc = (const int*)d_in[1];
    const int*   edst = (const int*)d_in[2];
    const float* ew   = (const float*)d_in[3];
    const float* l0w  = (const float*)d_in[4];
    const float* l0b  = (const float*)d_in[5];
    const float* cw   = (const float*)d_in[6];
    const float* l1w  = (const float*)d_in[7];
    const float* l1b  = (const float*)d_in[8];
    float* out = (float*)d_out;

    char* p = (char*)d_ws;
    unsigned short* h0 = (unsigned short*)p; p += (size_t)NNODES * HID * 2;  // 12.8MB
    unsigned short* hA = (unsigned short*)p; p += (size_t)NNODES * HID * 2;
    unsigned short* hB = (unsigned short*)p; p += (size_t)NNODES * HID * 2;
    int2*  srcw = (int2*)p;  p += ((size_t)NEDGES + 4 * NNODES) * 8;  // padded CSR
    int* offs     = (int*)p; p += (size_t)(NNODES + 1) * 4;
    int* bin_tot  = (int*)p; p += 1024;
    int* bin_base = (int*)p; p += 2048;   // 257 ints
    int* bin_cur  = (int*)p; p += 1024;
    int* bpad     = (int*)p; p += 1024;
    int* pbase    = (int*)p; p += 2048;   // 257 ints
    // Aliases (build runs BEFORE lin0/layers, all stream-ordered):
    //   bsrcw (3.2M int2 = 25.6MB) spans h0+hA (dead until lin0/layer-0);
    //   degb_g (256*6272*4 = 6.42MB) + nbase_g (256*392*4 = 401KB) live in hB
    //   (dead until layer-1 output).
    int2* bsrcw  = (int2*)h0;
    int* degb_g  = (int*)hB;
    int* nbase_g = (int*)((char*)hB + (size_t)7 * 1024 * 1024);

    hipMemsetAsync(bin_tot, 0, NBIN * sizeof(int), stream);

    const int nbb = (NEDGES + 2047) / 2048;       // 1563
    bin_count_kernel<<<nbb, 256, 0, stream>>>(edst, bin_tot);
    bin_scan_kernel<<<1, 256, 0, stream>>>(bin_tot, bin_base, bin_cur);
    bin_scatter_kernel<<<nbb, 256, 0, stream>>>(esrc, edst, ew, bin_cur, bsrcw);
    bin_hist_kernel<<<NBIN, 512, 0, stream>>>(bsrcw, bin_base, degb_g, nbase_g, bpad);
    pbase_scan_kernel<<<1, 256, 0, stream>>>(bpad, pbase, offs);
    bin_write_kernel<<<NBIN, 512, 0, stream>>>(bsrcw, bin_base, degb_g, nbase_g,
                                               pbase, srcw, offs);

    // lin0 AFTER the build: h0 region doubles as bsrcw during the build.
    lin0_kernel<<<(NNODES + 127) / 128, 256, 0, stream>>>(x, l0w, l0b, h0);

    const unsigned short* hin = h0;
    unsigned short* bufs[2] = { hA, hB };
    for (int l = 0; l < NLAYERS; ++l) {
        float beta = (float)log(0.5 / (double)(l + 1) + 1.0);
        unsigned short* hout = bufs[l & 1];
        spmm_layer_kernel<<<NNODES / NPB, 256, 0, stream>>>(
            hin, h0, hout, offs, srcw, cw + (size_t)l * HID * HID, beta);
        hin = hout;
    }
    final_kernel<<<NNODES / 4, 256, 0, stream>>>(hin, l1w, l1b, out);
}

// Round 8
// 1005.289 us; speedup vs baseline: 1.3267x; 1.0312x over previous
//
#include <hip/hip_runtime.h>
#include <math.h>

#define NNODES 100000
#define NEDGES 3200000
#define NFEAT  500
#define HID    64
#define NCLS   40
#define NLAYERS 8
#define NPB    16      // spmm nodes per block (quarter-wave gather: 4 nodes/wave)
#define NBUCK  16      // src-range buckets per node list (6250 nodes = 0.8MB bf16 rows)
#define NODES_PER_BUCK 6250
#define NBIN   256     // dst-range bins; one block per bin does the final sort
#define NPBIN  391     // nodes per bin (last bin: 295)
#define NKEY   (NPBIN * NBUCK)   // 6256 (node,bucket) keys per bin
#define DEGB_STRIDE 6272
#define NBASE_STRIDE 392

typedef __attribute__((ext_vector_type(8))) short short8;   // 8 bf16 (4 VGPRs)
typedef __attribute__((ext_vector_type(4))) float floatx4;  // MFMA acc

static __device__ __forceinline__ float b2f(unsigned short u) {
    return __uint_as_float(((unsigned)u) << 16);
}
static __device__ __forceinline__ unsigned short f2b(float f) {
    unsigned u = __float_as_uint(f);
    return (unsigned short)((u + 0x7FFFu + ((u >> 16) & 1u)) >> 16);  // RNE
}
static __device__ __forceinline__ ushort4 pk4(float4 v) {
    return make_ushort4(f2b(v.x), f2b(v.y), f2b(v.z), f2b(v.w));
}

// ---------------- lin0: h0 = relu(x @ W + b)  --  MFMA bf16 GEMM ----------------
__global__ __launch_bounds__(256) void lin0_kernel(const float* __restrict__ x,
    const float* __restrict__ w, const float* __restrict__ b,
    unsigned short* __restrict__ h0)
{
    __shared__ unsigned short as_[128][40];  // A tile bf16 [m][k], rows padded 32->40
    __shared__ unsigned short wt[64][40];    // W^T chunk bf16 [n][k]
    const int tid = threadIdx.x;
    const int wv = tid >> 6, lane = tid & 63;
    const int ln15 = lane & 15, q = lane >> 4;
    const int m0 = blockIdx.x * 128;

    floatx4 acc[2][4];
#pragma unroll
    for (int i = 0; i < 2; ++i)
#pragma unroll
        for (int t = 0; t < 4; ++t) acc[i][t] = (floatx4){0.f, 0.f, 0.f, 0.f};

    const int r_ = tid >> 1, hh = tid & 1;       // staging: row, 16-float half
    int gms = m0 + r_; if (gms >= NNODES) gms = NNODES - 1;
    const float* xrow = x + (size_t)gms * NFEAT;

    for (int c = 0; c < 16; ++c) {
        const int k0 = c * 32;
        // ---- stage A: 128 x 32 fp32 -> bf16 ----
        {
            float4 v0, v1, v2, v3;
            if (c < 15 || hh == 0) {
                const float4* p4 = (const float4*)(xrow + k0 + 16 * hh);
                v0 = p4[0]; v1 = p4[1]; v2 = p4[2]; v3 = p4[3];
            } else {  // tail: k 496..511, only 496..499 valid
                v0 = *(const float4*)(xrow + 496);
                v1 = make_float4(0, 0, 0, 0); v2 = v1; v3 = v1;
            }
            ushort4* dst4 = (ushort4*)&as_[r_][16 * hh];
            dst4[0] = pk4(v0); dst4[1] = pk4(v1); dst4[2] = pk4(v2); dst4[3] = pk4(v3);
        }
        // ---- stage W^T: 32 x 64 fp32 -> bf16 [n][k] ----
#pragma unroll
        for (int ii = 0; ii < 2; ++ii) {
            int i = tid + ii * 256;               // float4 index in chunk (512 total)
            int k = i >> 4, nb = (i & 15) * 4;
            float4 v = make_float4(0, 0, 0, 0);
            if (c < 15 || i < 320)                // k0+k < 500
                v = ((const float4*)(w + (size_t)k0 * HID))[i];
            wt[nb + 0][k] = f2b(v.x); wt[nb + 1][k] = f2b(v.y);
            wt[nb + 2][k] = f2b(v.z); wt[nb + 3][k] = f2b(v.w);
        }
        __syncthreads();
        // ---- frags + MFMA ----
        short8 af[2], bfr[4];
#pragma unroll
        for (int mt = 0; mt < 2; ++mt)
            af[mt] = *(const short8*)&as_[32 * wv + 16 * mt + ln15][8 * q];
#pragma unroll
        for (int t = 0; t < 4; ++t)
            bfr[t] = *(const short8*)&wt[16 * t + ln15][8 * q];
#pragma unroll
        for (int mt = 0; mt < 2; ++mt)
#pragma unroll
            for (int t = 0; t < 4; ++t)
                acc[mt][t] = __builtin_amdgcn_mfma_f32_16x16x32_bf16(
                    af[mt], bfr[t], acc[mt][t], 0, 0, 0);
        __syncthreads();
    }
    // ---- epilogue: C/D layout col=lane&15, row=q*4+reg ----
    float bv[4];
#pragma unroll
    for (int t = 0; t < 4; ++t) bv[t] = b[16 * t + ln15];
#pragma unroll
    for (int mt = 0; mt < 2; ++mt)
#pragma unroll
        for (int r = 0; r < 4; ++r) {
            int gm = m0 + 32 * wv + 16 * mt + q * 4 + r;
            if (gm < NNODES) {
#pragma unroll
                for (int t = 0; t < 4; ++t)
                    h0[(size_t)gm * HID + 16 * t + ln15] =
                        f2b(fmaxf(acc[mt][t][r] + bv[t], 0.f));
            }
        }
}

// ============ CSR build via single-writer-XCD LDS counting sort ============
// (round-7 verified: no multi-XCD dirty window -> no write amplification)

__global__ __launch_bounds__(256) void bin_count_kernel(const int* __restrict__ dst,
                                                        int* __restrict__ bin_tot)
{
    __shared__ int h[NBIN];
    h[threadIdx.x] = 0;
    __syncthreads();
    const int eb = blockIdx.x * 2048;
#pragma unroll
    for (int i = 0; i < 8; ++i) {
        int e = eb + i * 256 + threadIdx.x;
        if (e < NEDGES) {
            int d = __builtin_nontemporal_load(dst + e);
            atomicAdd(&h[d / NPBIN], 1);
        }
    }
    __syncthreads();
    if (h[threadIdx.x]) atomicAdd(&bin_tot[threadIdx.x], h[threadIdx.x]);
}

__global__ void bin_scan_kernel(const int* __restrict__ bin_tot,
                                int* __restrict__ bin_base, int* __restrict__ bin_cur)
{
    __shared__ int s[NBIN];
    const int t = threadIdx.x;        // 256 threads
    const int c = bin_tot[t];
    s[t] = c;
    __syncthreads();
    for (int off = 1; off < NBIN; off <<= 1) {
        int u = (t >= off) ? s[t - off] : 0;
        __syncthreads();
        s[t] += u;
        __syncthreads();
    }
    bin_base[t] = s[t] - c;
    bin_cur[t]  = s[t] - c;
    if (t == NBIN - 1) bin_base[NBIN] = s[t];    // = NEDGES
}

__global__ __launch_bounds__(256) void bin_scatter_kernel(const int* __restrict__ src,
    const int* __restrict__ dst, const float* __restrict__ w,
    int* __restrict__ bin_cur, int2* __restrict__ bsrcw)
{
    __shared__ int h[NBIN], base[NBIN];
    h[threadIdx.x] = 0;
    __syncthreads();
    const int eb = blockIdx.x * 2048;
    int dv[8], sv[8], bv[8]; float wv[8];
#pragma unroll
    for (int i = 0; i < 8; ++i) {
        int e = eb + i * 256 + threadIdx.x;
        if (e < NEDGES) {
            dv[i] = __builtin_nontemporal_load(dst + e);
            sv[i] = __builtin_nontemporal_load(src + e);
            wv[i] = __builtin_nontemporal_load(w + e);
            bv[i] = dv[i] / NPBIN;
            atomicAdd(&h[bv[i]], 1);
        } else dv[i] = -1;
    }
    __syncthreads();
    {
        int c = h[threadIdx.x];
        base[threadIdx.x] = c ? atomicAdd(&bin_cur[threadIdx.x], c) : 0;
        h[threadIdx.x] = 0;
    }
    __syncthreads();
#pragma unroll
    for (int i = 0; i < 8; ++i) {
        if (dv[i] >= 0) {
            int r = atomicAdd(&h[bv[i]], 1);
            int dl = dv[i] - bv[i] * NPBIN;
            bsrcw[base[bv[i]] + r] = make_int2((dl << 17) | sv[i], __float_as_int(wv[i]));
        }
    }
}

// one block per bin: key histogram + padded node scan; dumps cnt + node bases
__global__ __launch_bounds__(512) void bin_hist_kernel(const int2* __restrict__ bsrcw,
    const int* __restrict__ bin_base, int* __restrict__ degb_g,
    int* __restrict__ nbase_g, int* __restrict__ bpad)
{
    __shared__ int cnt[NKEY];
    __shared__ int nb[512];
    const int b = blockIdx.x, t = threadIdx.x;
    const int nn = min(NPBIN, NNODES - b * NPBIN);
    for (int k = t; k < NKEY; k += 512) cnt[k] = 0;
    __syncthreads();
    const int e0 = bin_base[b], e1 = bin_base[b + 1];
    for (int e = e0 + t; e < e1; e += 512) {
        int px = bsrcw[e].x;
        int key = (int)(((unsigned)px) >> 17) * NBUCK + (px & 0x1FFFF) / NODES_PER_BUCK;
        atomicAdd(&cnt[key], 1);
    }
    __syncthreads();
    int pdeg = 0;
    if (t < nn) {
        int run = 0;
#pragma unroll
        for (int k = 0; k < NBUCK; ++k) run += cnt[t * NBUCK + k];
        pdeg = (run + 3) & ~3;
    }
    nb[t] = pdeg;
    __syncthreads();
    for (int off = 1; off < 512; off <<= 1) {
        int u = (t >= off) ? nb[t - off] : 0;
        __syncthreads();
        nb[t] += u;
        __syncthreads();
    }
    if (t < nn) nbase_g[b * NBASE_STRIDE + t] = nb[t] - pdeg;
    if (t == nn - 1) {
        nbase_g[b * NBASE_STRIDE + nn] = nb[t];
        bpad[b] = nb[t];
    }
    for (int k = t; k < NKEY; k += 512) degb_g[(size_t)b * DEGB_STRIDE + k] = cnt[k];
}

__global__ void pbase_scan_kernel(const int* __restrict__ bpad,
                                  int* __restrict__ pbase, int* __restrict__ offs)
{
    __shared__ int s[NBIN];
    const int t = threadIdx.x;
    const int c = bpad[t];
    s[t] = c;
    __syncthreads();
    for (int off = 1; off < NBIN; off <<= 1) {
        int u = (t >= off) ? s[t - off] : 0;
        __syncthreads();
        s[t] += u;
        __syncthreads();
    }
    pbase[t] = s[t] - c;
    if (t == NBIN - 1) { pbase[NBIN] = s[t]; offs[NNODES] = s[t]; }
}

// one block per bin: rank via LDS atomics, write srcw + pads + offs
__global__ __launch_bounds__(512) void bin_write_kernel(const int2* __restrict__ bsrcw,
    const int* __restrict__ bin_base, const int* __restrict__ degb_g,
    const int* __restrict__ nbase_g, const int* __restrict__ pbase,
    int2* __restrict__ srcw, int* __restrict__ offs)
{
    __shared__ int kb[NKEY];
    __shared__ int nbs[NPBIN + 1];
    const int b = blockIdx.x, t = threadIdx.x;
    const int nn = min(NPBIN, NNODES - b * NPBIN);
    const int pb = pbase[b];
    for (int i = t; i <= nn; i += 512) nbs[i] = nbase_g[b * NBASE_STRIDE + i];
    __syncthreads();
    if (t < nn) {
        int run = nbs[t];
#pragma unroll
        for (int k = 0; k < NBUCK; ++k) {
            int c = degb_g[(size_t)b * DEGB_STRIDE + t * NBUCK + k];
            kb[t * NBUCK + k] = run;
            run += c;
        }
    }
    __syncthreads();
    const int e0 = bin_base[b], e1 = bin_base[b + 1];
    for (int e = e0 + t; e < e1; e += 512) {
        int2 p = bsrcw[e];
        int s = p.x & 0x1FFFF;
        int key = (int)(((unsigned)p.x) >> 17) * NBUCK + s / NODES_PER_BUCK;
        int pos = atomicAdd(&kb[key], 1);
        srcw[pb + pos] = make_int2(s * 128, p.y);   // byte offset, weight
    }
    __syncthreads();
    if (t < nn) {
        int e = kb[t * NBUCK + NBUCK - 1];          // = nbs[t] + deg[t]
        const int ep = nbs[t + 1];                  // = nbs[t] + padded deg
        for (; e < ep; ++e) srcw[pb + e] = make_int2(0, 0);
        offs[b * NPBIN + t] = pb + nbs[t];
    }
}

// ---------------- fused SpMM + blend + dense + relu layer ----------------
// Gather is exposed-latency-bound (r7 analysis: BW floor ~20us, measured ~99us).
// Fix: LDS-staged edge lists -- each quarter bulk-stages 32 srcw entries with
// ONE int4 global load per lane (1 vmcnt exposure / 32 edges, was 1 per 4),
// then the inner loop reads addr+weight from LDS (same-wave lockstep, no
// barrier) and issues 8 independent h-loads per step. swb rows padded to 33
// so the 4 quarters' broadcast ds_read_b64 hit distinct banks.
__global__ __launch_bounds__(256) void spmm_layer_kernel(
    const unsigned short* __restrict__ h_in, const unsigned short* __restrict__ x0,
    unsigned short* __restrict__ h_out, const int* __restrict__ offs,
    const int2* __restrict__ srcw, const float* __restrict__ Wg, float beta)
{
    __shared__ float          zs [NPB][72];  // f32 z (residual term)
    __shared__ unsigned short zsb[NPB][72];  // bf16 z (MFMA A operand)
    __shared__ unsigned short WbT[HID][72];  // bf16 W^T: WbT[j][k] = Wg[k][j]
    __shared__ int2           swb[NPB][33];  // staged edges, +1 pad (bank spread)
    const int tid = threadIdx.x;

    // ---- stage WbT (fp32 -> bf16, transposed) ----
    for (int i = tid; i < 1024; i += 256) {
        float4 v = ((const float4*)Wg)[i];
        int k = i >> 4, j = (i & 15) * 4;
        WbT[j + 0][k] = f2b(v.x); WbT[j + 1][k] = f2b(v.y);
        WbT[j + 2][k] = f2b(v.z); WbT[j + 3][k] = f2b(v.w);
    }

    const int wv = tid >> 6, lane = tid & 63;
    const int qt = lane >> 4, ln = lane & 15;   // quarter id, lane-in-quarter
    const int nloc = wv * 4 + qt;               // local node 0..15
    const int n = blockIdx.x * NPB + nloc;
    int e = offs[n];
    const int e1 = offs[n + 1];
    const char* hbl = (const char*)h_in + ln * 8;
    // independent: issue x0 load early, consumed after the gather loop
    const uint2 xv = *(const uint2*)((const char*)x0 + (size_t)n * 128 + ln * 8);

    float a0 = 0.f, a1 = 0.f, a2 = 0.f, a3 = 0.f;
    for (; e < e1; e += 32) {
        const int ec = min(32, e1 - e);
        {   // stage 32 entries: lane ln loads srcw[e+2ln .. e+2ln+1] (16B, aligned:
            // e % 4 == 0 since all degrees padded x4). Over-read past e1 stays
            // inside srcw's 100K-entry allocation slack.
            int4 tq = *(const int4*)(srcw + e + 2 * ln);
            swb[nloc][2 * ln]     = make_int2(tq.x, tq.y);
            swb[nloc][2 * ln + 1] = make_int2(tq.z, tq.w);
        }
        int j = 0;
        for (; j + 8 <= ec; j += 8) {   // 8 independent h-loads in flight
            int2 q0 = swb[nloc][j + 0], q1 = swb[nloc][j + 1];
            int2 q2 = swb[nloc][j + 2], q3 = swb[nloc][j + 3];
            int2 q4 = swb[nloc][j + 4], q5 = swb[nloc][j + 5];
            int2 q6 = swb[nloc][j + 6], q7 = swb[nloc][j + 7];
            uint2 v0 = *(const uint2*)(hbl + q0.x);
            uint2 v1 = *(const uint2*)(hbl + q1.x);
            uint2 v2 = *(const uint2*)(hbl + q2.x);
            uint2 v3 = *(const uint2*)(hbl + q3.x);
            uint2 v4 = *(const uint2*)(hbl + q4.x);
            uint2 v5 = *(const uint2*)(hbl + q5.x);
            uint2 v6 = *(const uint2*)(hbl + q6.x);
            uint2 v7 = *(const uint2*)(hbl + q7.x);
            float w0 = __int_as_float(q0.y), w1 = __int_as_float(q1.y);
            float w2 = __int_as_float(q2.y), w3 = __int_as_float(q3.y);
            float w4 = __int_as_float(q4.y), w5 = __int_as_float(q5.y);
            float w6 = __int_as_float(q6.y), w7 = __int_as_float(q7.y);
            a0 = fmaf(w0, __uint_as_float(v0.x << 16), a0);
            a1 = fmaf(w0, __uint_as_float(v0.x & 0xffff0000u), a1);
            a2 = fmaf(w0, __uint_as_float(v0.y << 16), a2);
            a3 = fmaf(w0, __uint_as_float(v0.y & 0xffff0000u), a3);
            a0 = fmaf(w1, __uint_as_float(v1.x << 16), a0);
            a1 = fmaf(w1, __uint_as_float(v1.x & 0xffff0000u), a1);
            a2 = fmaf(w1, __uint_as_float(v1.y << 16), a2);
            a3 = fmaf(w1, __uint_as_float(v1.y & 0xffff0000u), a3);
            a0 = fmaf(w2, __uint_as_float(v2.x << 16), a0);
            a1 = fmaf(w2, __uint_as_float(v2.x & 0xffff0000u), a1);
            a2 = fmaf(w2, __uint_as_float(v2.y << 16), a2);
            a3 = fmaf(w2, __uint_as_float(v2.y & 0xffff0000u), a3);
            a0 = fmaf(w3, __uint_as_float(v3.x << 16), a0);
            a1 = fmaf(w3, __uint_as_float(v3.x & 0xffff0000u), a1);
            a2 = fmaf(w3, __uint_as_float(v3.y << 16), a2);
            a3 = fmaf(w3, __uint_as_float(v3.y & 0xffff0000u), a3);
            a0 = fmaf(w4, __uint_as_float(v4.x << 16), a0);
            a1 = fmaf(w4, __uint_as_float(v4.x & 0xffff0000u), a1);
            a2 = fmaf(w4, __uint_as_float(v4.y << 16), a2);
            a3 = fmaf(w4, __uint_as_float(v4.y & 0xffff0000u), a3);
            a0 = fmaf(w5, __uint_as_float(v5.x << 16), a0);
            a1 = fmaf(w5, __uint_as_float(v5.x & 0xffff0000u), a1);
            a2 = fmaf(w5, __uint_as_float(v5.y << 16), a2);
            a3 = fmaf(w5, __uint_as_float(v5.y & 0xffff0000u), a3);
            a0 = fmaf(w6, __uint_as_float(v6.x << 16), a0);
            a1 = fmaf(w6, __uint_as_float(v6.x & 0xffff0000u), a1);
            a2 = fmaf(w6, __uint_as_float(v6.y << 16), a2);
            a3 = fmaf(w6, __uint_as_float(v6.y & 0xffff0000u), a3);
            a0 = fmaf(w7, __uint_as_float(v7.x << 16), a0);
            a1 = fmaf(w7, __uint_as_float(v7.x & 0xffff0000u), a1);
            a2 = fmaf(w7, __uint_as_float(v7.y << 16), a2);
            a3 = fmaf(w7, __uint_as_float(v7.y & 0xffff0000u), a3);
        }
        if (j < ec) {   // 4-edge tail (ec % 4 == 0)
            int2 q0 = swb[nloc][j + 0], q1 = swb[nloc][j + 1];
            int2 q2 = swb[nloc][j + 2], q3 = swb[nloc][j + 3];
            uint2 v0 = *(const uint2*)(hbl + q0.x);
            uint2 v1 = *(const uint2*)(hbl + q1.x);
            uint2 v2 = *(const uint2*)(hbl + q2.x);
            uint2 v3 = *(const uint2*)(hbl + q3.x);
            float w0 = __int_as_float(q0.y), w1 = __int_as_float(q1.y);
            float w2 = __int_as_float(q2.y), w3 = __int_as_float(q3.y);
            a0 = fmaf(w0, __uint_as_float(v0.x << 16), a0);
            a1 = fmaf(w0, __uint_as_float(v0.x & 0xffff0000u), a1);
            a2 = fmaf(w0, __uint_as_float(v0.y << 16), a2);
            a3 = fmaf(w0, __uint_as_float(v0.y & 0xffff0000u), a3);
            a0 = fmaf(w1, __uint_as_float(v1.x << 16), a0);
            a1 = fmaf(w1, __uint_as_float(v1.x & 0xffff0000u), a1);
            a2 = fmaf(w1, __uint_as_float(v1.y << 16), a2);
            a3 = fmaf(w1, __uint_as_float(v1.y & 0xffff0000u), a3);
            a0 = fmaf(w2, __uint_as_float(v2.x << 16), a0);
            a1 = fmaf(w2, __uint_as_float(v2.x & 0xffff0000u), a1);
            a2 = fmaf(w2, __uint_as_float(v2.y << 16), a2);
            a3 = fmaf(w2, __uint_as_float(v2.y & 0xffff0000u), a3);
            a0 = fmaf(w3, __uint_as_float(v3.x << 16), a0);
            a1 = fmaf(w3, __uint_as_float(v3.x & 0xffff0000u), a1);
            a2 = fmaf(w3, __uint_as_float(v3.y << 16), a2);
            a3 = fmaf(w3, __uint_as_float(v3.y & 0xffff0000u), a3);
        }
    }
    // blend with initial residual x0 (bf16), write f32 + bf16 copies of z
    float z0 = 0.9f * a0 + 0.1f * __uint_as_float(xv.x << 16);
    float z1 = 0.9f * a1 + 0.1f * __uint_as_float(xv.x & 0xffff0000u);
    float z2 = 0.9f * a2 + 0.1f * __uint_as_float(xv.y << 16);
    float z3 = 0.9f * a3 + 0.1f * __uint_as_float(xv.y & 0xffff0000u);
    *(float4*)&zs[nloc][4 * ln] = make_float4(z0, z1, z2, z3);
    *(ushort4*)&zsb[nloc][4 * ln] = make_ushort4(f2b(z0), f2b(z1), f2b(z2), f2b(z3));
    __syncthreads();

    // ---- dense phase: mm = z @ W via MFMA. wave wv owns N-tile cols 16wv..16wv+15.
    floatx4 acc = (floatx4){0.f, 0.f, 0.f, 0.f};
#pragma unroll
    for (int s = 0; s < 2; ++s) {
        short8 af = *(const short8*)&zsb[ln][32 * s + 8 * qt];
        short8 bf = *(const short8*)&WbT[16 * wv + ln][32 * s + 8 * qt];
        acc = __builtin_amdgcn_mfma_f32_16x16x32_bf16(af, bf, acc, 0, 0, 0);
    }
    // C layout: col = lane&15 (j in tile), row = qt*4 + reg  -> row = node
    const float ob = 1.f - beta;
    const size_t base = (size_t)blockIdx.x * NPB;
#pragma unroll
    for (int r4 = 0; r4 < 4; ++r4) {
        const int node = qt * 4 + r4;
        const int j = 16 * wv + ln;
        float hv = fmaxf(ob * zs[node][j] + beta * acc[r4], 0.f);
        h_out[(base + node) * HID + j] = f2b(hv);
    }
}

// ---------------- final: log_softmax(h @ W1 + b1) ----------------
__global__ __launch_bounds__(256) void final_kernel(const unsigned short* __restrict__ h,
    const float* __restrict__ w1, const float* __restrict__ b1, float* __restrict__ out)
{
    const int m = threadIdx.x >> 6, j = threadIdx.x & 63;
    const long n = (long)blockIdx.x * 4 + m;
    const int jj = (j < NCLS) ? j : NCLS - 1;
    const ushort4* hrow = (const ushort4*)(h + n * HID);
    float acc = b1[jj];
#pragma unroll
    for (int k4 = 0; k4 < 16; ++k4) {
        ushort4 hv = hrow[k4];
        const int k = k4 * 4;
        acc = fmaf(b2f(hv.x), w1[(k + 0) * NCLS + jj], acc);
        acc = fmaf(b2f(hv.y), w1[(k + 1) * NCLS + jj], acc);
        acc = fmaf(b2f(hv.z), w1[(k + 2) * NCLS + jj], acc);
        acc = fmaf(b2f(hv.w), w1[(k + 3) * NCLS + jj], acc);
    }
    float lg = (j < NCLS) ? acc : -INFINITY;
    float mx = lg;
#pragma unroll
    for (int o = 32; o > 0; o >>= 1) mx = fmaxf(mx, __shfl_xor(mx, o, 64));
    float ex = (j < NCLS) ? expf(acc - mx) : 0.f;
    float sm = ex;
#pragma unroll
    for (int o = 32; o > 0; o >>= 1) sm += __shfl_xor(sm, o, 64);
    if (j < NCLS) out[n * NCLS + j] = acc - mx - logf(sm);
}

extern "C" void kernel_launch(void* const* d_in, const int* in_sizes, int n_in,
                              void* d_out, int out_size, void* d_ws, size_t ws_size,
                              hipStream_t stream)
{
    const float* x    = (const float*)d_in[0];
    const int*   esrc = (const int*)d_in[1];
    const int*   edst = (const int*)d_in[2];
    const float* ew   = (const float*)d_in[3];
    const float* l0w  = (const float*)d_in[4];
    const float* l0b  = (const float*)d_in[5];
    const float* cw   = (const float*)d_in[6];
    const float* l1w  = (const float*)d_in[7];
    const float* l1b  = (const float*)d_in[8];
    float* out = (float*)d_out;

    char* p = (char*)d_ws;
    unsigned short* h0 = (unsigned short*)p; p += (size_t)NNODES * HID * 2;  // 12.8MB
    unsigned short* hA = (unsigned short*)p; p += (size_t)NNODES * HID * 2;
    unsigned short* hB = (unsigned short*)p; p += (size_t)NNODES * HID * 2;
    int2*  srcw = (int2*)p;  p += ((size_t)NEDGES + 4 * NNODES) * 8;  // padded CSR
    int* offs     = (int*)p; p += (size_t)(NNODES + 1) * 4;
    int* bin_tot  = (int*)p; p += 1024;
    int* bin_base = (int*)p; p += 2048;   // 257 ints
    int* bin_cur  = (int*)p; p += 1024;
    int* bpad     = (int*)p; p += 1024;
    int* pbase    = (int*)p; p += 2048;   // 257 ints
    // Aliases (build runs BEFORE lin0/layers, all stream-ordered):
    //   bsrcw (3.2M int2 = 25.6MB) spans h0+hA (dead until lin0/layer-0);
    //   degb_g (256*6272*4 = 6.42MB) + nbase_g (256*392*4 = 401KB) live in hB
    //   (dead until layer-1 output).
    int2* bsrcw  = (int2*)h0;
    int* degb_g  = (int*)hB;
    int* nbase_g = (int*)((char*)hB + (size_t)7 * 1024 * 1024);

    hipMemsetAsync(bin_tot, 0, NBIN * sizeof(int), stream);

    const int nbb = (NEDGES + 2047) / 2048;       // 1563
    bin_count_kernel<<<nbb, 256, 0, stream>>>(edst, bin_tot);
    bin_scan_kernel<<<1, 256, 0, stream>>>(bin_tot, bin_base, bin_cur);
    bin_scatter_kernel<<<nbb, 256, 0, stream>>>(esrc, edst, ew, bin_cur, bsrcw);
    bin_hist_kernel<<<NBIN, 512, 0, stream>>>(bsrcw, bin_base, degb_g, nbase_g, bpad);
    pbase_scan_kernel<<<1, 256, 0, stream>>>(bpad, pbase, offs);
    bin_write_kernel<<<NBIN, 512, 0, stream>>>(bsrcw, bin_base, degb_g, nbase_g,
                                               pbase, srcw, offs);

    // lin0 AFTER the build: h0 region doubles as bsrcw during the build.
    lin0_kernel<<<(NNODES + 127) / 128, 256, 0, stream>>>(x, l0w, l0b, h0);

    const unsigned short* hin = h0;
    unsigned short* bufs[2] = { hA, hB };
    for (int l = 0; l < NLAYERS; ++l) {
        float beta = (float)log(0.5 / (double)(l + 1) + 1.0);
        unsigned short* hout = bufs[l & 1];
        spmm_layer_kernel<<<NNODES / NPB, 256, 0, stream>>>(
            hin, h0, hout, offs, srcw, cw + (size_t)l * HID * HID, beta);
        hin = hout;
    }
    final_kernel<<<NNODES / 4, 256, 0, stream>>>(hin, l1w, l1b, out);
}